// Round 5
// baseline (259.473 us; speedup 1.0000x reference)
//
#include <hip/hip_runtime.h>

#define BATCH 4
#define NPTS 8192
#define DIM 128
#define TOTAL_ROWS (BATCH * NPTS)   // 32768
#define SLICES 4                    // m-slices per batch
#define SLICE_W 2048                // cols per slice
#define ITERS 128                   // 16-col tiles per slice

typedef __attribute__((ext_vector_type(8))) short bf16x8;
typedef __attribute__((ext_vector_type(4))) float f32x4;

// fp32 -> bf16 round-to-nearest-even
__device__ __forceinline__ unsigned short f2bf(float x) {
  unsigned u = __float_as_uint(x);
  u += 0x7FFFu + ((u >> 16) & 1u);
  return (unsigned short)(u >> 16);
}
// monotonic encoding of float for unsigned atomicMin (handles negatives)
__device__ __forceinline__ unsigned encf(float f) {
  unsigned b = __float_as_uint(f);
  return (b & 0x80000000u) ? ~b : (b | 0x80000000u);
}
__device__ __forceinline__ float decf(unsigned u) {
  unsigned b = (u & 0x80000000u) ? (u ^ 0x80000000u) : ~u;
  return __uint_as_float(b);
}

// ---- fused: fp32 -> bf16 convert of f_, plus row norms gn2 ----
__global__ void convert_gn2_kernel(const float* __restrict__ in,
                                   unsigned short* __restrict__ out,
                                   float* __restrict__ gn2) {
  int idx = blockIdx.x * 256 + threadIdx.x;     // one per 8 elements
  const float4* ip = (const float4*)in + (size_t)idx * 2;
  float4 a = ip[0], b = ip[1];
  union { unsigned short us[8]; uint4 u4; } p;
  p.us[0] = f2bf(a.x); p.us[1] = f2bf(a.y); p.us[2] = f2bf(a.z); p.us[3] = f2bf(a.w);
  p.us[4] = f2bf(b.x); p.us[5] = f2bf(b.y); p.us[6] = f2bf(b.z); p.us[7] = f2bf(b.w);
  ((uint4*)out)[idx] = p.u4;
  float s = 0.f;
  s = fmaf(a.x, a.x, s); s = fmaf(a.y, a.y, s);
  s = fmaf(a.z, a.z, s); s = fmaf(a.w, a.w, s);
  s = fmaf(b.x, b.x, s); s = fmaf(b.y, b.y, s);
  s = fmaf(b.z, b.z, s); s = fmaf(b.w, b.w, s);
  s += __shfl_xor(s, 1); s += __shfl_xor(s, 2);
  s += __shfl_xor(s, 4); s += __shfl_xor(s, 8);
  if ((threadIdx.x & 15) == 0) gn2[idx >> 4] = s;
}

// ---- main: per wave, 32 f-rows (A in regs) x 2048-col slice ----
// T=2 keeps total reg demand ~105 < 128 -> 4 waves/SIMD; grid 1024 = 4 blocks/CU
__global__ __launch_bounds__(256, 4)
void chamfer_mfma_kernel(const float* __restrict__ f,
                         const unsigned short* __restrict__ gbf,
                         const float* __restrict__ gn2,
                         unsigned int* __restrict__ rowmin,
                         unsigned int* __restrict__ colmin) {
  const int lane = threadIdx.x & 63;
  const int l15  = lane & 15;
  const int q    = lane >> 4;                       // 0..3
  const int widx = threadIdx.x >> 6;                // 0..3

  // XCD-aware: 2 (b,slice) combos per XCD, 64 row-groups each
  const int bid   = blockIdx.x;                     // 0..1023
  const int combo = (bid & 7) * 2 + ((bid >> 3) & 1);  // 0..15
  const int b     = combo >> 2;
  const int slice = combo & 3;
  const int rgrp  = bid >> 4;                       // 0..63
  const int r0    = rgrp * 128 + widx * 32;
  const int mbase = slice * SLICE_W;
  const int bN    = b * NPTS;

  // block-level column-min accumulator (encoded floats, gn2 NOT included)
  __shared__ unsigned cl[SLICE_W];
  #pragma unroll
  for (int k = 0; k < SLICE_W / 256; ++k)
    cl[threadIdx.x + k * 256] = 0xFFFFFFFFu;
  __syncthreads();

  // ---- A fragments (2 tiles x 4 k-chunks) + fn2 per C-row, in-flight ----
  bf16x8 af[2][4];
  float fn2r[2][4];
  const float* fb = f + (size_t)bN * DIM;
  #pragma unroll
  for (int t = 0; t < 2; ++t) {
    const float* frow = fb + (size_t)(r0 + t * 16 + l15) * DIM + q * 8;
    float s = 0.f;
    #pragma unroll
    for (int kc = 0; kc < 4; ++kc) {
      float4 x = *(const float4*)(frow + kc * 32);
      float4 y = *(const float4*)(frow + kc * 32 + 4);
      bf16x8 v;
      v[0] = (short)f2bf(x.x); v[1] = (short)f2bf(x.y);
      v[2] = (short)f2bf(x.z); v[3] = (short)f2bf(x.w);
      v[4] = (short)f2bf(y.x); v[5] = (short)f2bf(y.y);
      v[6] = (short)f2bf(y.z); v[7] = (short)f2bf(y.w);
      af[t][kc] = v;
      s = fmaf(x.x, x.x, s); s = fmaf(x.y, x.y, s);
      s = fmaf(x.z, x.z, s); s = fmaf(x.w, x.w, s);
      s = fmaf(y.x, y.x, s); s = fmaf(y.y, y.y, s);
      s = fmaf(y.z, y.z, s); s = fmaf(y.w, y.w, s);
    }
    s += __shfl_xor(s, 16); s += __shfl_xor(s, 32);   // lane holds fn2 of row (l&15)
    #pragma unroll
    for (int i = 0; i < 4; ++i) fn2r[t][i] = __shfl(s, (q << 2) + i);
  }

  float rmin[2][4];
  #pragma unroll
  for (int t = 0; t < 2; ++t)
    #pragma unroll
    for (int i = 0; i < 4; ++i) rmin[t][i] = 3.4e38f;

  const unsigned short* gb  = gbf + (size_t)bN * DIM;
  const float*          gnb = gn2 + bN;

  auto loadB = [&](int mt, bf16x8 bfr[4], float& gv) {
    const int m0 = mbase + mt * 16;
    const unsigned short* grow = gb + (size_t)(m0 + l15) * DIM + q * 8;
    #pragma unroll
    for (int kc = 0; kc < 4; ++kc) bfr[kc] = *(const bf16x8*)(grow + kc * 32);
    gv = gnb[m0 + l15];
  };

  auto compute = [&](const bf16x8 bfr[4], float gv, int mt) {
    f32x4 acc[2];
    #pragma unroll
    for (int t = 0; t < 2; ++t) {
      f32x4 a = {0.f, 0.f, 0.f, 0.f};
      #pragma unroll
      for (int kc = 0; kc < 4; ++kc)
        a = __builtin_amdgcn_mfma_f32_16x16x32_bf16(af[t][kc], bfr[kc], a, 0, 0, 0);
      acc[t] = a;
    }
    // rowmin tracks min_m (gn2[m] - 2dot); colmin tracks min_n (fn2[n] - 2dot)
    float cm[2];
    #pragma unroll
    for (int t = 0; t < 2; ++t) {
      float e0 = fmaf(-2.f, acc[t][0], fn2r[t][0]);
      float e1 = fmaf(-2.f, acc[t][1], fn2r[t][1]);
      float e2 = fmaf(-2.f, acc[t][2], fn2r[t][2]);
      float e3 = fmaf(-2.f, acc[t][3], fn2r[t][3]);
      cm[t] = fminf(fminf(e0, e1), fminf(e2, e3));
      #pragma unroll
      for (int i = 0; i < 4; ++i)
        rmin[t][i] = fminf(rmin[t][i], fmaf(-2.f, acc[t][i], gv));
    }
    float cmin = fminf(cm[0], cm[1]);
    // all 64 lanes: fire-and-forget LDS atomic (4-way same-address per col)
    atomicMin(&cl[mt * 16 + l15], encf(cmin));
  };

  // ping-pong double buffer, unroll by 2 (no register copies)
  bf16x8 bA[4], bB[4];
  float gA, gB;
  loadB(0, bA, gA);
  for (int mt = 0; mt < ITERS; mt += 2) {
    loadB(mt + 1, bB, gB);
    compute(bA, gA, mt);
    loadB((mt + 2) & (ITERS - 1), bA, gA);
    compute(bB, gB, mt + 1);
  }

  // finalize row mins: reduce over the 16 column-lanes, add fn2
  #pragma unroll
  for (int t = 0; t < 2; ++t)
    #pragma unroll
    for (int i = 0; i < 4; ++i) {
      float v = rmin[t][i];
      v = fminf(v, __shfl_xor(v, 1));
      v = fminf(v, __shfl_xor(v, 2));
      v = fminf(v, __shfl_xor(v, 4));
      v = fminf(v, __shfl_xor(v, 8));
      v += fn2r[t][i];
      if (l15 == 0)
        atomicMin(&rowmin[bN + r0 + t * 16 + q * 4 + i], encf(v));
    }

  // merge block-level col mins into global (one atomic per col per block)
  __syncthreads();
  #pragma unroll
  for (int k = 0; k < SLICE_W / 256; ++k) {
    int c = threadIdx.x + k * 256;
    atomicMin(&colmin[bN + mbase + c], cl[c]);
  }
}

// ---- reduction stage 1: 128 blocks x 256 thr (adds deferred gn2 to colmin) ----
__global__ void reduce1_kernel(const unsigned int* __restrict__ rowmin,
                               const unsigned int* __restrict__ colmin,
                               const float* __restrict__ gn2,
                               float* __restrict__ partial) {
  __shared__ float sbuf[4];
  int i = blockIdx.x * 256 + threadIdx.x;
  float s = decf(rowmin[i]) + (decf(colmin[i]) + gn2[i]);
  #pragma unroll
  for (int o = 32; o >= 1; o >>= 1) s += __shfl_xor(s, o);
  if ((threadIdx.x & 63) == 0) sbuf[threadIdx.x >> 6] = s;
  __syncthreads();
  if (threadIdx.x == 0)
    partial[blockIdx.x] = sbuf[0] + sbuf[1] + sbuf[2] + sbuf[3];
}

// ---- reduction stage 2: 1 block, 64 thr ----
__global__ void reduce2_kernel(const float* __restrict__ partial,
                               float* __restrict__ out) {
  float s = partial[threadIdx.x] + partial[threadIdx.x + 64];
  #pragma unroll
  for (int o = 32; o >= 1; o >>= 1) s += __shfl_xor(s, o);
  if (threadIdx.x == 0) out[0] = s / (float)TOTAL_ROWS;
}

extern "C" void kernel_launch(void* const* d_in, const int* in_sizes, int n_in,
                              void* d_out, int out_size, void* d_ws, size_t ws_size,
                              hipStream_t stream) {
  (void)in_sizes; (void)n_in; (void)out_size; (void)ws_size;
  const float* f  = (const float*)d_in[0];
  const float* f_ = (const float*)d_in[1];

  char* ws = (char*)d_ws;
  unsigned short* gbf = (unsigned short*)ws;                       // 8 MiB bf16 copy of f_
  float* gn2 = (float*)(ws + 8u * 1024u * 1024u);                  // 128 KiB
  unsigned int* rowmin = (unsigned int*)(gn2 + TOTAL_ROWS);        // 128 KiB
  unsigned int* colmin = rowmin + TOTAL_ROWS;                      // 128 KiB
  float* partial = (float*)(colmin + TOTAL_ROWS);                  // 512 B

  convert_gn2_kernel<<<2048, 256, 0, stream>>>(f_, gbf, gn2);
  hipMemsetAsync(rowmin, 0xFF, (size_t)TOTAL_ROWS * 4, stream);
  hipMemsetAsync(colmin, 0xFF, (size_t)TOTAL_ROWS * 4, stream);
  chamfer_mfma_kernel<<<1024, 256, 0, stream>>>(f, gbf, gn2, rowmin, colmin);
  reduce1_kernel<<<128, 256, 0, stream>>>(rowmin, colmin, gn2, partial);
  reduce2_kernel<<<1, 64, 0, stream>>>(partial, (float*)d_out);
}

// Round 6
// 92.095 us; speedup vs baseline: 2.8175x; 2.8175x over previous
//
#include <hip/hip_runtime.h>

#define BATCH 4
#define NPTS 8192
#define DIM 128
#define TOTAL_ROWS (BATCH * NPTS)   // 32768
#define SLICES 4                    // m-slices per batch
#define SLICE_W 2048                // cols per slice
#define ITERS 128                   // 16-col tiles per slice
#define TILES_PER_B 512             // NPTS/16

typedef __attribute__((ext_vector_type(8))) short bf16x8;
typedef __attribute__((ext_vector_type(4))) float f32x4;

// fp32 -> bf16 round-to-nearest-even
__device__ __forceinline__ unsigned short f2bf(float x) {
  unsigned u = __float_as_uint(x);
  u += 0x7FFFu + ((u >> 16) & 1u);
  return (unsigned short)(u >> 16);
}
// monotonic encoding of float for unsigned atomicMin (handles negatives)
__device__ __forceinline__ unsigned encf(float f) {
  unsigned b = __float_as_uint(f);
  return (b & 0x80000000u) ? ~b : (b | 0x80000000u);
}
__device__ __forceinline__ float decf(unsigned u) {
  unsigned b = (u & 0x80000000u) ? (u ^ 0x80000000u) : ~u;
  return __uint_as_float(b);
}

// ---- pack f_ into MFMA-fragment order (bf16) ----
// pk layout: frag index = ((b*512 + mtg)*4 + kc)*64 + lane, lane = q*16 + l15
// value: 8 bf16 of g[b][mtg*16 + l15][kc*32 + q*8 .. +7]
// hot-loop load becomes base + lane*16B  -> perfectly coalesced
__global__ void pack_b_kernel(const float* __restrict__ in,
                              unsigned short* __restrict__ pk) {
  int tid = blockIdx.x * 256 + threadIdx.x;        // one fragment per thread
  int l15 = tid & 15;
  int q   = (tid >> 4) & 3;
  int kc  = (tid >> 6) & 3;
  int mtg = (tid >> 8) & (TILES_PER_B - 1);
  int b   = tid >> 17;
  const float* src = in + ((size_t)(b * NPTS + mtg * 16 + l15) * DIM) + kc * 32 + q * 8;
  float4 x = ((const float4*)src)[0];
  float4 y = ((const float4*)src)[1];
  union { unsigned short us[8]; uint4 u4; } p;
  p.us[0] = f2bf(x.x); p.us[1] = f2bf(x.y); p.us[2] = f2bf(x.z); p.us[3] = f2bf(x.w);
  p.us[4] = f2bf(y.x); p.us[5] = f2bf(y.y); p.us[6] = f2bf(y.z); p.us[7] = f2bf(y.w);
  ((uint4*)pk)[tid] = p.u4;                        // coalesced write
}

// ---- squared row norms of f_: 64 rows/block, 4 threads/row ----
__global__ void norms_kernel(const float* __restrict__ x, float* __restrict__ n2) {
  int tid  = threadIdx.x;
  int row  = blockIdx.x * 64 + (tid >> 2);
  int part = tid & 3;
  const float4* xp = (const float4*)(x + (size_t)row * DIM) + part * 8;
  float s = 0.f;
  #pragma unroll
  for (int j = 0; j < 8; ++j) {
    float4 v = xp[j];
    s = fmaf(v.x, v.x, s); s = fmaf(v.y, v.y, s);
    s = fmaf(v.z, v.z, s); s = fmaf(v.w, v.w, s);
  }
  s += __shfl_xor(s, 1);
  s += __shfl_xor(s, 2);
  if (part == 0) n2[row] = s;
}

// ---- main: per wave, 64 f-rows (A in regs) x 2048-col slice ----
// grid 512 = 2 blocks/CU; LB(256,2) => 256-VGPR budget, no spill (R3-proven)
__global__ __launch_bounds__(256, 2)
void chamfer_mfma_kernel(const float* __restrict__ f,
                         const unsigned short* __restrict__ pk,
                         const float* __restrict__ gn2,
                         unsigned int* __restrict__ rowmin,
                         unsigned int* __restrict__ colmin) {
  const int lane = threadIdx.x & 63;
  const int l15  = lane & 15;
  const int q    = lane >> 4;                       // 0..3
  const int widx = threadIdx.x >> 6;                // 0..3

  // XCD-aware: 2 (b,slice) combos per XCD, 32 row-groups each
  const int bid   = blockIdx.x;                     // 0..511
  const int combo = (bid & 7) * 2 + ((bid >> 3) & 1);  // 0..15
  const int b     = combo >> 2;
  const int slice = combo & 3;
  const int rgrp  = bid >> 4;                       // 0..31
  const int r0    = rgrp * 256 + widx * 64;
  const int bN    = b * NPTS;
  const int tile0 = b * TILES_PER_B + slice * ITERS;  // first packed tile index

  // block-level column-min accumulator (encoded floats, gn2 NOT included)
  __shared__ unsigned cl[SLICE_W];
  #pragma unroll
  for (int k = 0; k < SLICE_W / 256; ++k)
    cl[threadIdx.x + k * 256] = 0xFFFFFFFFu;
  __syncthreads();

  // ---- A fragments (4 tiles x 4 k-chunks) + fn2 per C-row, in-flight ----
  bf16x8 af[4][4];
  float fn2r[4][4];
  const float* fb = f + (size_t)bN * DIM;
  #pragma unroll
  for (int t = 0; t < 4; ++t) {
    const float* frow = fb + (size_t)(r0 + t * 16 + l15) * DIM + q * 8;
    float s = 0.f;
    #pragma unroll
    for (int kc = 0; kc < 4; ++kc) {
      float4 x = *(const float4*)(frow + kc * 32);
      float4 y = *(const float4*)(frow + kc * 32 + 4);
      bf16x8 v;
      v[0] = (short)f2bf(x.x); v[1] = (short)f2bf(x.y);
      v[2] = (short)f2bf(x.z); v[3] = (short)f2bf(x.w);
      v[4] = (short)f2bf(y.x); v[5] = (short)f2bf(y.y);
      v[6] = (short)f2bf(y.z); v[7] = (short)f2bf(y.w);
      af[t][kc] = v;
      s = fmaf(x.x, x.x, s); s = fmaf(x.y, x.y, s);
      s = fmaf(x.z, x.z, s); s = fmaf(x.w, x.w, s);
      s = fmaf(y.x, y.x, s); s = fmaf(y.y, y.y, s);
      s = fmaf(y.z, y.z, s); s = fmaf(y.w, y.w, s);
    }
    s += __shfl_xor(s, 16); s += __shfl_xor(s, 32);   // lane holds fn2 of row (l&15)
    #pragma unroll
    for (int i = 0; i < 4; ++i) fn2r[t][i] = __shfl(s, (q << 2) + i);
  }

  float rmin[4][4];
  #pragma unroll
  for (int t = 0; t < 4; ++t)
    #pragma unroll
    for (int i = 0; i < 4; ++i) rmin[t][i] = 3.4e38f;

  // packed fragment base for this wave's lane (contiguous 1KB per kc)
  const unsigned short* pkw = pk + ((size_t)tile0 * 4) * 512 + lane * 8;
  const float*          gnb = gn2 + bN + slice * SLICE_W;

  auto loadB = [&](int mt, bf16x8 bfr[4], float& gv) {
    const unsigned short* base = pkw + (size_t)mt * 2048;   // 4 kc * 512 ushorts
    #pragma unroll
    for (int kc = 0; kc < 4; ++kc) bfr[kc] = *(const bf16x8*)(base + kc * 512);
    gv = gnb[mt * 16 + l15];
  };

  auto compute = [&](const bf16x8 bfr[4], float gv, int mt) {
    f32x4 acc[4];
    #pragma unroll
    for (int t = 0; t < 4; ++t) {
      f32x4 a = {0.f, 0.f, 0.f, 0.f};
      #pragma unroll
      for (int kc = 0; kc < 4; ++kc)
        a = __builtin_amdgcn_mfma_f32_16x16x32_bf16(af[t][kc], bfr[kc], a, 0, 0, 0);
      acc[t] = a;
    }
    // rowmin tracks min_m (gn2[m] - 2dot); colmin tracks min_n (fn2[n] - 2dot)
    float cm[4];
    #pragma unroll
    for (int t = 0; t < 4; ++t) {
      float e0 = fmaf(-2.f, acc[t][0], fn2r[t][0]);
      float e1 = fmaf(-2.f, acc[t][1], fn2r[t][1]);
      float e2 = fmaf(-2.f, acc[t][2], fn2r[t][2]);
      float e3 = fmaf(-2.f, acc[t][3], fn2r[t][3]);
      cm[t] = fminf(fminf(e0, e1), fminf(e2, e3));
      #pragma unroll
      for (int i = 0; i < 4; ++i)
        rmin[t][i] = fminf(rmin[t][i], fmaf(-2.f, acc[t][i], gv));
    }
    float cmin = fminf(fminf(cm[0], cm[1]), fminf(cm[2], cm[3]));
    // all 64 lanes: fire-and-forget LDS atomic (4-way same-address per col)
    atomicMin(&cl[mt * 16 + l15], encf(cmin));
  };

  // ping-pong double buffer, unroll by 2 (no register copies)
  bf16x8 bA[4], bB[4];
  float gA, gB;
  loadB(0, bA, gA);
  for (int mt = 0; mt < ITERS; mt += 2) {
    loadB(mt + 1, bB, gB);
    compute(bA, gA, mt);
    loadB((mt + 2) & (ITERS - 1), bA, gA);
    compute(bB, gB, mt + 1);
  }

  // finalize row mins: reduce over the 16 column-lanes, add fn2
  #pragma unroll
  for (int t = 0; t < 4; ++t)
    #pragma unroll
    for (int i = 0; i < 4; ++i) {
      float v = rmin[t][i];
      v = fminf(v, __shfl_xor(v, 1));
      v = fminf(v, __shfl_xor(v, 2));
      v = fminf(v, __shfl_xor(v, 4));
      v = fminf(v, __shfl_xor(v, 8));
      v += fn2r[t][i];
      if (l15 == 0)
        atomicMin(&rowmin[bN + r0 + t * 16 + q * 4 + i], encf(v));
    }

  // merge block-level col mins into global (one atomic per col per block)
  __syncthreads();
  #pragma unroll
  for (int k = 0; k < SLICE_W / 256; ++k) {
    int c = threadIdx.x + k * 256;
    atomicMin(&colmin[bN + slice * SLICE_W + c], cl[c]);
  }
}

// ---- reduction stage 1: 128 blocks x 256 thr (adds deferred gn2 to colmin) ----
__global__ void reduce1_kernel(const unsigned int* __restrict__ rowmin,
                               const unsigned int* __restrict__ colmin,
                               const float* __restrict__ gn2,
                               float* __restrict__ partial) {
  __shared__ float sbuf[4];
  int i = blockIdx.x * 256 + threadIdx.x;
  float s = decf(rowmin[i]) + (decf(colmin[i]) + gn2[i]);
  #pragma unroll
  for (int o = 32; o >= 1; o >>= 1) s += __shfl_xor(s, o);
  if ((threadIdx.x & 63) == 0) sbuf[threadIdx.x >> 6] = s;
  __syncthreads();
  if (threadIdx.x == 0)
    partial[blockIdx.x] = sbuf[0] + sbuf[1] + sbuf[2] + sbuf[3];
}

// ---- reduction stage 2: 1 block, 64 thr ----
__global__ void reduce2_kernel(const float* __restrict__ partial,
                               float* __restrict__ out) {
  float s = partial[threadIdx.x] + partial[threadIdx.x + 64];
  #pragma unroll
  for (int o = 32; o >= 1; o >>= 1) s += __shfl_xor(s, o);
  if (threadIdx.x == 0) out[0] = s / (float)TOTAL_ROWS;
}

extern "C" void kernel_launch(void* const* d_in, const int* in_sizes, int n_in,
                              void* d_out, int out_size, void* d_ws, size_t ws_size,
                              hipStream_t stream) {
  (void)in_sizes; (void)n_in; (void)out_size; (void)ws_size;
  const float* f  = (const float*)d_in[0];
  const float* f_ = (const float*)d_in[1];

  char* ws = (char*)d_ws;
  unsigned short* pk = (unsigned short*)ws;                        // 8 MiB packed bf16 f_
  float* gn2 = (float*)(ws + 8u * 1024u * 1024u);                  // 128 KiB
  unsigned int* rowmin = (unsigned int*)(gn2 + TOTAL_ROWS);        // 128 KiB
  unsigned int* colmin = rowmin + TOTAL_ROWS;                      // 128 KiB
  float* partial = (float*)(colmin + TOTAL_ROWS);                  // 512 B

  pack_b_kernel<<<2048, 256, 0, stream>>>(f_, pk);
  norms_kernel<<<512, 256, 0, stream>>>(f_, gn2);
  hipMemsetAsync(rowmin, 0xFF, (size_t)TOTAL_ROWS * 4, stream);
  hipMemsetAsync(colmin, 0xFF, (size_t)TOTAL_ROWS * 4, stream);
  chamfer_mfma_kernel<<<512, 256, 0, stream>>>(f, pk, gn2, rowmin, colmin);
  reduce1_kernel<<<128, 256, 0, stream>>>(rowmin, colmin, gn2, partial);
  reduce2_kernel<<<1, 64, 0, stream>>>(partial, (float*)d_out);
}